// Round 3
// baseline (272.244 us; speedup 1.0000x reference)
//
#include <hip/hip_runtime.h>

#define N_NODES_C 100000
#define N_EDGES_C 1200000
#define NUM_GRAPHS_C 64
#define D_C 64
#define NPASS_C 8
#define BN_EPS_C 1e-5f
#define SCAN_B 391  // ceil(100000/256)

typedef unsigned short u16;
typedef unsigned int u32;

using frag_ab = __attribute__((ext_vector_type(8))) short;  // 8 bf16 (4 VGPRs)
using f32x4   = __attribute__((ext_vector_type(4))) float;

__device__ __forceinline__ u16 f2bf(float f) {  // RTNE
    u32 x = __float_as_uint(f);
    x += 0x7fffu + ((x >> 16) & 1u);
    return (u16)(x >> 16);
}
__device__ __forceinline__ float bf2f(u16 u) {
    return __uint_as_float(((u32)u) << 16);
}

// ------------- prep: x->bf16, W->bf16[n][k], zero row, + COUNT ------------
// Count phase fused here: pos[e] = atomicAdd(&cnt[dst[e]],1). The atomic
// latency overlaps prep's dense streaming converts (different pipes).
__global__ void k_prep(const float* __restrict__ x,
                       const float* __restrict__ W1, const float* __restrict__ W2,
                       const int* __restrict__ dst,
                       u16* __restrict__ Xb, u16* __restrict__ Wb1,
                       u16* __restrict__ Wb2, u16* __restrict__ T,
                       int* __restrict__ cnt, int* __restrict__ pos) {
    int i = blockIdx.x * 256 + threadIdx.x;  // 1.6M threads
    int base = i * 4;
    if (base < N_NODES_C * D_C) {
        float4 f = *(const float4*)(x + base);
        ushort4 o;
        o.x = f2bf(f.x); o.y = f2bf(f.y); o.z = f2bf(f.z); o.w = f2bf(f.w);
        *(ushort4*)(Xb + base) = o;
    }
    if (i < 4096) {  // W[k][n] -> Wb[n][k]
        int n = i >> 6, k = i & 63;
        Wb1[i] = f2bf(W1[k * 64 + n]);
        Wb2[i] = f2bf(W2[k * 64 + n]);
    }
    if (i < 64) T[(size_t)N_NODES_C * 64 + i] = 0;  // zero row (survives gemms)
    if (i < N_EDGES_C) {
        int d = dst[i];
        pos[i] = atomicAdd(&cnt[d], 1);
    }
}

// --------------------- exclusive scan: cnt -> start -----------------------
__global__ void __launch_bounds__(256) k_scan1(const int* __restrict__ cnt,
                                               int* __restrict__ start,
                                               int* __restrict__ bsum) {
    __shared__ int sh[256];
    int t = threadIdx.x;
    int i = blockIdx.x * 256 + t;
    int c = (i < N_NODES_C) ? cnt[i] : 0;
    int val = c;
    sh[t] = val;
    __syncthreads();
#pragma unroll
    for (int off = 1; off < 256; off <<= 1) {
        int y = (t >= off) ? sh[t - off] : 0;
        __syncthreads();
        val += y;
        sh[t] = val;
        __syncthreads();
    }
    if (i < N_NODES_C) start[i] = val - c;  // block-local exclusive
    if (t == 255) bsum[blockIdx.x] = val;   // block total
}

__global__ void __launch_bounds__(512) k_scan2(int* __restrict__ bsum) {
    __shared__ int sh[512];
    int t = threadIdx.x;
    int c = (t < SCAN_B) ? bsum[t] : 0;
    int val = c;
    sh[t] = val;
    __syncthreads();
#pragma unroll
    for (int off = 1; off < 512; off <<= 1) {
        int y = (t >= off) ? sh[t - off] : 0;
        __syncthreads();
        val += y;
        sh[t] = val;
        __syncthreads();
    }
    if (t < SCAN_B) bsum[t] = val - c;  // exclusive block offsets, in place
}

__global__ void __launch_bounds__(256) k_scan3(int* __restrict__ start,
                                               const int* __restrict__ bsum) {
    int i = blockIdx.x * 256 + threadIdx.x;
    if (i < N_NODES_C) start[i] += bsum[blockIdx.x];
}

// ------------------- place: atomic-free CSR fill, XCD-swizzled ------------
// pass = blockIdx & 7: all blocks owning dst-range `pass` share one XCD.
// CSR is dense (4.8 MB): every col line is fully covered by writes, and the
// per-XCD active slice (~600 KB) lives in its 4 MB L2 until complete ->
// write-allocate fills and re-dirty evictions (R2: 37.5 MB FETCH / 56 MB
// WRITE) collapse to ~1x the payload. No atomics: slot = start[dst]+pos[e].
__global__ void __launch_bounds__(256) k_place(
        const int* __restrict__ src, const int* __restrict__ dst,
        const int* __restrict__ pos, const int* __restrict__ start,
        int* __restrict__ col) {
    int pass = blockIdx.x & (NPASS_C - 1);
    int chunk = blockIdx.x >> 3;
    int nchunks = gridDim.x >> 3;
    const int RANGE = N_NODES_C / NPASS_C;  // 12500
    int lo = pass * RANGE;
    int hi = (pass == NPASS_C - 1) ? N_NODES_C : lo + RANGE;
    const int nquads = N_EDGES_C / 4;  // 300000
    int tid = chunk * 256 + threadIdx.x;
    int nthreads = nchunks * 256;
    const int4* dst4 = (const int4*)dst;
    const int4* src4 = (const int4*)src;
    const int4* pos4 = (const int4*)pos;
    for (int i = tid; i < nquads; i += nthreads) {
        int4 d4 = dst4[i];
        int dd[4] = {d4.x, d4.y, d4.z, d4.w};
        bool in0 = dd[0] >= lo && dd[0] < hi;
        bool in1 = dd[1] >= lo && dd[1] < hi;
        bool in2 = dd[2] >= lo && dd[2] < hi;
        bool in3 = dd[3] >= lo && dd[3] < hi;
        if (in0 | in1 | in2 | in3) {
            int4 s4 = src4[i];
            int4 p4 = pos4[i];
            int ss[4] = {s4.x, s4.y, s4.z, s4.w};
            int pp[4] = {p4.x, p4.y, p4.z, p4.w};
            bool in[4] = {in0, in1, in2, in3};
#pragma unroll
            for (int k = 0; k < 4; ++k) {
                if (in[k]) {
                    col[(size_t)(u32)(start[dd[k]] + pp[k])] = ss[k];
                }
            }
        }
    }
}

// ------------------- GEMM via MFMA 16x16x32 bf16 --------------------------
__global__ void __launch_bounds__(256) k_gemm_mfma(
        const u16* __restrict__ Xb, const u16* __restrict__ Wb,
        const int* __restrict__ cnt, u16* __restrict__ T) {
    int lane = threadIdx.x & 63;
    int q = lane >> 4, ln = lane & 15;
    int wave = blockIdx.x * 4 + (threadIdx.x >> 6);
    int nwaves = gridDim.x * 4;
    frag_ab bfr[4][2];
#pragma unroll
    for (int nt = 0; nt < 4; ++nt)
#pragma unroll
        for (int kh = 0; kh < 2; ++kh)
            bfr[nt][kh] = *(const frag_ab*)(Wb + (nt * 16 + ln) * 64 + kh * 32 + q * 8);
    const int nstrips = N_NODES_C / 16;
    for (int s = wave; s < nstrips; s += nwaves) {
        int r0 = s * 16;
        frag_ab a0 = *(const frag_ab*)(Xb + (size_t)(r0 + ln) * 64 + q * 8);
        frag_ab a1 = *(const frag_ab*)(Xb + (size_t)(r0 + ln) * 64 + 32 + q * 8);
        f32x4 acc[4];
#pragma unroll
        for (int nt = 0; nt < 4; ++nt) {
            acc[nt] = (f32x4){0.f, 0.f, 0.f, 0.f};
            acc[nt] = __builtin_amdgcn_mfma_f32_16x16x32_bf16(a0, bfr[nt][0], acc[nt], 0, 0, 0);
            acc[nt] = __builtin_amdgcn_mfma_f32_16x16x32_bf16(a1, bfr[nt][1], acc[nt], 0, 0, 0);
        }
        float di[4];
#pragma unroll
        for (int reg = 0; reg < 4; ++reg)
            di[reg] = rsqrtf((float)(cnt[r0 + q * 4 + reg] + 1));
#pragma unroll
        for (int nt = 0; nt < 4; ++nt)
#pragma unroll
            for (int reg = 0; reg < 4; ++reg)
                T[(size_t)(r0 + q * 4 + reg) * 64 + nt * 16 + ln] =
                    f2bf(acc[nt][reg] * di[reg]);
    }
}

// ------------------- gather: CSR, 4 rows / load, zero-row padding ---------
// Lane (h,c): h=lane>>4 picks row-slot, c=lane&15 picks 4 bf16 cols (uint2).
// CSR col read: col[start[p] + lane] (one dword/lane, ~deg useful). start
// and cnt are uniform s_loads prefetched 2 nodes ahead; the col vector for
// node p+1 is issued at the top of node p's body (one T-loop of slack).
template <bool POOL>
__device__ __forceinline__ void gather_body(
        const u16* __restrict__ T, const int* __restrict__ col,
        const int* __restrict__ cnt, const int* __restrict__ start,
        const float* __restrict__ b, const float* __restrict__ g,
        const float* __restrict__ be, const float* __restrict__ m,
        const float* __restrict__ v, const int* __restrict__ batch,
        u16* __restrict__ Ab, float* __restrict__ pooled) {
    const int ZROW = N_NODES_C;
    int lane = threadIdx.x & 63;
    int h = lane >> 4, c = lane & 15;
    int cbase = c << 2;
    int wave = blockIdx.x * 4 + (threadIdx.x >> 6);
    int nwaves = gridDim.x * 4;
    float scv[4], c0v[4];
#pragma unroll
    for (int i = 0; i < 4; ++i) {
        float sci = g[cbase + i] * rsqrtf(v[cbase + i] + BN_EPS_C);
        scv[i] = sci;
        c0v[i] = (b[cbase + i] - m[cbase + i]) * sci + be[cbase + i];
    }
    const int chunk = (N_NODES_C + nwaves - 1) / nwaves;
    int p0 = wave * chunk;
    int p1 = p0 + chunk; if (p1 > N_NODES_C) p1 = N_NODES_C;
    if (p0 >= p1) return;

    float psum = 0.f; int curg = -1;

    // pipeline prologue: meta for p0, p0+1; col vector for p0
    int d0 = cnt[p0];
    int s0 = start[p0];
    int d1 = 0, s1 = 0;
    if (p0 + 1 < p1) { d1 = cnt[p0 + 1]; s1 = start[p0 + 1]; }
    int cv0 = col[(size_t)(u32)s0 + lane];

    for (int p = p0; p < p1; ++p) {
        int deg = __builtin_amdgcn_readfirstlane(d0);
        int cvR = cv0;
        if (p + 1 < p1) {  // rotate pipeline: col for p+1, meta for p+2
            cv0 = col[(size_t)(u32)s1 + lane];
            d0 = d1;
            if (p + 2 < p1) { d1 = cnt[p + 2]; s1 = start[p + 2]; }
        }
        if (deg > 63) deg = 63;
        // clean index vector: [neighbors | self | ZROW pad...]
        int cv = (lane < deg) ? cvR : ((lane == deg) ? p : ZROW);
        int iters = (deg + 4) >> 2;  // ceil((deg+1)/4), slots incl. self
        float a0 = 0.f, a1 = 0.f, a2 = 0.f, a3 = 0.f;
        int sl = h;
        int j = 0;
        for (; j + 2 <= iters; j += 2) {
            int i0 = __shfl(cv, sl);
            int i1 = __shfl(cv, sl + 4);
            uint2 t0 = *(const uint2*)(T + (((size_t)(u32)i0) << 6) + (c << 2));
            uint2 t1 = *(const uint2*)(T + (((size_t)(u32)i1) << 6) + (c << 2));
            a0 += __uint_as_float(t0.x << 16); a1 += __uint_as_float(t0.x & 0xffff0000u);
            a2 += __uint_as_float(t0.y << 16); a3 += __uint_as_float(t0.y & 0xffff0000u);
            a0 += __uint_as_float(t1.x << 16); a1 += __uint_as_float(t1.x & 0xffff0000u);
            a2 += __uint_as_float(t1.y << 16); a3 += __uint_as_float(t1.y & 0xffff0000u);
            sl += 8;
        }
        if (j < iters) {
            int i0 = __shfl(cv, sl);
            uint2 t0 = *(const uint2*)(T + (((size_t)(u32)i0) << 6) + (c << 2));
            a0 += __uint_as_float(t0.x << 16); a1 += __uint_as_float(t0.x & 0xffff0000u);
            a2 += __uint_as_float(t0.y << 16); a3 += __uint_as_float(t0.y & 0xffff0000u);
        }
        // reduce across the 4 h-groups
        a0 += __shfl_xor(a0, 16); a0 += __shfl_xor(a0, 32);
        a1 += __shfl_xor(a1, 16); a1 += __shfl_xor(a1, 32);
        a2 += __shfl_xor(a2, 16); a2 += __shfl_xor(a2, 32);
        a3 += __shfl_xor(a3, 16); a3 += __shfl_xor(a3, 32);
        float dr = rsqrtf((float)(deg + 1));
        if (POOL) {
            float asel = (h & 2) ? ((h & 1) ? a3 : a2) : ((h & 1) ? a1 : a0);
            float scl  = (h & 2) ? ((h & 1) ? scv[3] : scv[2]) : ((h & 1) ? scv[1] : scv[0]);
            float c0l  = (h & 2) ? ((h & 1) ? c0v[3] : c0v[2]) : ((h & 1) ? c0v[1] : c0v[0]);
            float vh = fmaxf(fmaf(asel * dr, scl, c0l), 0.f);
            int gg = batch[p];
            if (gg != curg) {
                if (curg >= 0) atomicAdd(&pooled[curg * 64 + cbase + h], psum);
                curg = gg; psum = 0.f;
            }
            psum += vh;
        } else {
            float v0 = fmaxf(fmaf(a0 * dr, scv[0], c0v[0]), 0.f);
            float v1 = fmaxf(fmaf(a1 * dr, scv[1], c0v[1]), 0.f);
            float v2 = fmaxf(fmaf(a2 * dr, scv[2], c0v[2]), 0.f);
            float v3 = fmaxf(fmaf(a3 * dr, scv[3], c0v[3]), 0.f);
            if (h == 0) {
                u32 w0 = (u32)f2bf(v0) | ((u32)f2bf(v1) << 16);
                u32 w1 = (u32)f2bf(v2) | ((u32)f2bf(v3) << 16);
                *(uint2*)(Ab + (((size_t)(u32)p) << 6) + (c << 2)) = make_uint2(w0, w1);
            }
        }
    }
    if (POOL && curg >= 0) atomicAdd(&pooled[curg * 64 + cbase + h], psum);
}

__global__ void __launch_bounds__(256) k_gather1(
        const u16* __restrict__ T, const int* __restrict__ col,
        const int* __restrict__ cnt, const int* __restrict__ start,
        const float* __restrict__ b, const float* __restrict__ g,
        const float* __restrict__ be, const float* __restrict__ m,
        const float* __restrict__ v, u16* __restrict__ Ab) {
    gather_body<false>(T, col, cnt, start, b, g, be, m, v, nullptr, Ab, nullptr);
}

__global__ void __launch_bounds__(256) k_gather2(
        const u16* __restrict__ T, const int* __restrict__ col,
        const int* __restrict__ cnt, const int* __restrict__ start,
        const float* __restrict__ b, const float* __restrict__ g,
        const float* __restrict__ be, const float* __restrict__ m,
        const float* __restrict__ v, const int* __restrict__ batch,
        float* __restrict__ pooled) {
    gather_body<true>(T, col, cnt, start, b, g, be, m, v, batch, nullptr, pooled);
}

// ----------------------------- classifier --------------------------------
__global__ void k_final(const float* __restrict__ pooled, const int* __restrict__ batch,
                        const float* __restrict__ Wc, const float* __restrict__ bc,
                        float* __restrict__ out) {
    __shared__ float sp[64 * 65];
    __shared__ int sub[64];
    int t = threadIdx.x;  // 256 threads
    for (int i = t; i < 4096; i += 256) sp[(i >> 6) * 65 + (i & 63)] = pooled[i];
    if (t < 64) {
        int lo = 0, hi = N_NODES_C;
        while (lo < hi) { int mid = (lo + hi) >> 1; if (batch[mid] > t) hi = mid; else lo = mid + 1; }
        sub[t] = lo;  // first index with batch > t
    }
    __syncthreads();
    if (t < 64) {
        int gi = t;
        int lb = gi ? sub[gi - 1] : 0;
        int cntg = sub[gi] - lb;
        float inv = 1.0f / fmaxf((float)cntg, 1.0f);
        float a0 = 0.f, a1 = 0.f;
#pragma unroll 8
        for (int f = 0; f < 64; ++f) {
            float p = sp[gi * 65 + f];
            a0 = fmaf(p, Wc[f * 2 + 0], a0);
            a1 = fmaf(p, Wc[f * 2 + 1], a1);
        }
        out[gi * 2 + 0] = a0 * inv + bc[0];
        out[gi * 2 + 1] = a1 * inv + bc[1];
    }
}

extern "C" void kernel_launch(void* const* d_in, const int* in_sizes, int n_in,
                              void* d_out, int out_size, void* d_ws, size_t ws_size,
                              hipStream_t stream) {
    const float* x    = (const float*)d_in[0];
    const int*   ei   = (const int*)d_in[1];
    const int*   batch= (const int*)d_in[2];
    const float* W1 = (const float*)d_in[3];
    const float* b1 = (const float*)d_in[4];
    const float* g1 = (const float*)d_in[5];
    const float* be1= (const float*)d_in[6];
    const float* m1 = (const float*)d_in[7];
    const float* v1 = (const float*)d_in[8];
    const float* W2 = (const float*)d_in[9];
    const float* b2 = (const float*)d_in[10];
    const float* g2 = (const float*)d_in[11];
    const float* be2= (const float*)d_in[12];
    const float* m2 = (const float*)d_in[13];
    const float* v2 = (const float*)d_in[14];
    const float* Wc = (const float*)d_in[15];
    const float* bc = (const float*)d_in[16];
    float* out = (float*)d_out;

    char* ws = (char*)d_ws;
    size_t off = 0;
    auto alloc = [&](size_t bytes) {
        size_t o = off;
        off = (off + bytes + 511) & ~(size_t)511;
        return o;
    };
    size_t o_cnt   = alloc((size_t)N_NODES_C * 4);
    size_t o_pool  = alloc((size_t)NUM_GRAPHS_C * D_C * 4);
    size_t zero_bytes = off;  // [cnt | pooled] zeroed each call
    size_t o_col   = alloc((size_t)(N_EDGES_C + 64) * 4);  // CSR 4.8 MB (+pad)
    size_t o_pos   = alloc((size_t)N_EDGES_C * 4);         // per-edge slot
    size_t o_start = alloc((size_t)(N_NODES_C + 64) * 4);  // CSR row starts
    size_t o_bsum  = alloc(512 * 4);
    size_t o_xb    = alloc((size_t)N_NODES_C * D_C * 2);
    size_t o_wb1   = alloc(4096 * 2);
    size_t o_wb2   = alloc(4096 * 2);
    size_t o_t     = alloc((size_t)(N_NODES_C + 1) * D_C * 2);  // +1: zero row
    size_t o_ab    = alloc((size_t)N_NODES_C * D_C * 2);  // bf16 activations
    (void)ws_size; (void)in_sizes; (void)n_in; (void)out_size;

    int*   cnt    = (int*)(ws + o_cnt);
    float* pooled = (float*)(ws + o_pool);
    int*   col    = (int*)(ws + o_col);
    int*   pos    = (int*)(ws + o_pos);
    int*   startp = (int*)(ws + o_start);
    int*   bsum   = (int*)(ws + o_bsum);
    u16*   Xb     = (u16*)(ws + o_xb);
    u16*   Wb1    = (u16*)(ws + o_wb1);
    u16*   Wb2    = (u16*)(ws + o_wb2);
    u16*   T      = (u16*)(ws + o_t);
    u16*   Ab     = (u16*)(ws + o_ab);

    const int* srcp = ei;
    const int* dstp = ei + N_EDGES_C;

    hipMemsetAsync(ws, 0, zero_bytes, stream);

    int pblocks = (N_NODES_C * D_C / 4 + 255) / 256;  // 6250 (1.6M threads)
    int sblocks = 2048;   // 256 chunks x 8 XCD-swizzled ranges
    int gblocks = 2048;   // 8192 persistent waves
    int mblocks = 1563;   // 6252 waves: one 16-row strip each
    k_prep<<<pblocks, 256, 0, stream>>>(x, W1, W2, dstp, Xb, Wb1, Wb2, T, cnt, pos);
    k_scan1<<<SCAN_B, 256, 0, stream>>>(cnt, startp, bsum);
    k_scan2<<<1, 512, 0, stream>>>(bsum);
    k_scan3<<<SCAN_B, 256, 0, stream>>>(startp, bsum);
    k_place<<<sblocks, 256, 0, stream>>>(srcp, dstp, pos, startp, col);

    k_gemm_mfma<<<mblocks, 256, 0, stream>>>(Xb, Wb1, cnt, T);
    k_gather1<<<gblocks, 256, 0, stream>>>(T, col, cnt, startp, b1, g1, be1, m1, v1, Ab);
    k_gemm_mfma<<<mblocks, 256, 0, stream>>>(Ab, Wb2, cnt, T);
    k_gather2<<<gblocks, 256, 0, stream>>>(T, col, cnt, startp, b2, g2, be2, m2, v2,
                                           batch, pooled);
    k_final<<<1, 256, 0, stream>>>(pooled, batch, Wc, bc, out);
}